// Round 4
// baseline (42.095 us; speedup 1.0000x reference)
//
#include <hip/hip_runtime.h>

#define BINS 10
#define BLOCK 256
#define GRID 2048

#define LOG2E 1.44269504088896340736f
#define LN2   0.69314718055994530942f

// ---------------------------------------------------------------------------
// For logit x with one-hot target bit tg, let y = tg ? -x : x. Then
//   g   = |sigmoid(x) - tg| = sigmoid(y) = u/(1+u),      u = e^y
//   bce = max(x,0) - x*tg + log1p(exp(-|x|)) = softplus(y) = ln(1+u)
// One exp2 + one rcp + one log2 per logit, no branches, no fabs.
// ---------------------------------------------------------------------------

__global__ void ghmc_init(double* ws) {
    int i = threadIdx.x;
    if (i < 2 * BINS) ws[i] = 0.0;
}

// hist column = tid (float2 -> bank pair (2*tid)%32, bin stride 2048 B == 0 mod banks)
__device__ __forceinline__ void proc(float y, float2* __restrict__ hbase) {
    y = fminf(fmaxf(y, -80.0f), 80.0f);              // v_med3_f32, NaN/overflow guard
    float u  = __builtin_amdgcn_exp2f(y * LOG2E);    // e^y
    float d  = 1.0f + u;
    float r  = __builtin_amdgcn_rcpf(d);
    float lg = __builtin_amdgcn_logf(d);             // log2(1+u)
    float sg = u * r;                                // sigmoid(y) = g in [0,1]
    float sp = lg * LN2;                             // softplus(y) = bce
    int b = (int)(sg * 10.0f);
    b = b > (BINS - 1) ? (BINS - 1) : b;
    float2* h = hbase + (b << 8);                    // + b*BLOCK float2s
    float2 v = *h;                                   // ds_read_b64
    v.x += 1.0f;
    v.y += sp;
    *h = v;                                          // ds_write_b64
}

// row (x0,x1) with target t in {0,1}: class0 flips iff t==0, class1 iff t==1.
// Send the two logits to DIFFERENT hist copies to break the DS RMW chain.
__device__ __forceinline__ void proc_row(float x0, float x1, int t,
                                         float2* __restrict__ hA,
                                         float2* __restrict__ hB) {
    unsigned s0 = (unsigned)(t ^ 1) << 31;
    unsigned s1 = s0 ^ 0x80000000u;
    proc(__uint_as_float(__float_as_uint(x0) ^ s0), hA);
    proc(__uint_as_float(__float_as_uint(x1) ^ s1), hB);
}

template <int WRITE_MODE>  // 0 = per-block partials (deterministic), 1 = double atomics
__global__ __launch_bounds__(BLOCK, 4) void ghmc_main(
    const float4* __restrict__ pred4,   // one float4 = 2 rows' logits
    const int4*   __restrict__ tgt4,    // one int4   = 4 rows' targets (int32)
    float2* __restrict__ partials,      // [GRID][BINS] (mode 0)
    double* __restrict__ wsd,           // [2*BINS]     (mode 1)
    int nQuads, int nRows)
{
    __shared__ float2 histA[BINS][BLOCK];   // 20 KiB
    __shared__ float2 histB[BINS][BLOCK];   // 20 KiB  (independent object -> DS ops may overlap)
    const int tid = threadIdx.x;
#pragma unroll
    for (int b = 0; b < BINS; ++b) {
        histA[b][tid] = make_float2(0.f, 0.f);
        histB[b][tid] = make_float2(0.f, 0.f);
    }
    // no sync needed: each thread touches only its own column until reduction

    float2* hA = &histA[0][tid];
    float2* hB = &histB[0][tid];

    for (int i = blockIdx.x * BLOCK + tid; i < nQuads; i += GRID * BLOCK) {
        float4 pa = pred4[2 * i + 0];   // rows 4i, 4i+1
        float4 pb = pred4[2 * i + 1];   // rows 4i+2, 4i+3
        int4   tq = tgt4[i];
        proc_row(pa.x, pa.y, tq.x, hA, hB);
        proc_row(pa.z, pa.w, tq.y, hA, hB);
        proc_row(pb.x, pb.y, tq.z, hA, hB);
        proc_row(pb.z, pb.w, tq.w, hA, hB);
    }

    // defensive scalar tail (N divisible by 4 here)
    if (blockIdx.x == 0 && tid == 0) {
        const float* pf = (const float*)pred4;
        const int*   tf = (const int*)tgt4;
        for (int r = nQuads * 4; r < nRows; ++r)
            proc_row(pf[2 * r], pf[2 * r + 1], tf[r], hA, hB);
    }

    // merge B into A (own column only -> no sync needed before)
#pragma unroll
    for (int b = 0; b < BINS; ++b) {
        float2 a = histA[b][tid], c = histB[b][tid];
        histA[b][tid] = make_float2(a.x + c.x, a.y + c.y);
    }
    __syncthreads();

    // 256 -> 128 -> 64 in LDS, then wave-0 shuffle reduce
    if (tid < 128) {
#pragma unroll
        for (int b = 0; b < BINS; ++b) {
            float2 x = histA[b][tid], y = histA[b][tid + 128];
            histA[b][tid] = make_float2(x.x + y.x, x.y + y.y);
        }
    }
    __syncthreads();
    if (tid < 64) {
        float cx[BINS], cy[BINS];
#pragma unroll
        for (int b = 0; b < BINS; ++b) {
            float2 x = histA[b][tid], y = histA[b][tid + 64];
            cx[b] = x.x + y.x;
            cy[b] = x.y + y.y;
        }
#pragma unroll
        for (int off = 32; off > 0; off >>= 1) {
#pragma unroll
            for (int b = 0; b < BINS; ++b) {
                cx[b] += __shfl_down(cx[b], off, 64);
                cy[b] += __shfl_down(cy[b], off, 64);
            }
        }
        if (tid == 0) {
            if (WRITE_MODE == 0) {
#pragma unroll
                for (int b = 0; b < BINS; ++b)
                    partials[blockIdx.x * BINS + b] = make_float2(cx[b], cy[b]);
            } else {
#pragma unroll
                for (int b = 0; b < BINS; ++b) {
                    atomicAdd(&wsd[b],        (double)cx[b]);
                    atomicAdd(&wsd[BINS + b], (double)cy[b]);
                }
            }
        }
    }
}

__global__ __launch_bounds__(1024) void ghmc_final_grid(
    const float2* __restrict__ partials, float* __restrict__ out, int nb)
{
    const int tid  = threadIdx.x;
    const int wid  = tid >> 6;
    const int lane = tid & 63;
    double cx[BINS], cy[BINS];
#pragma unroll
    for (int b = 0; b < BINS; ++b) { cx[b] = 0.0; cy[b] = 0.0; }

    for (int p = tid; p < nb; p += 1024) {
#pragma unroll
        for (int b = 0; b < BINS; ++b) {
            float2 v = partials[p * BINS + b];
            cx[b] += (double)v.x;
            cy[b] += (double)v.y;
        }
    }
#pragma unroll
    for (int off = 32; off > 0; off >>= 1) {
#pragma unroll
        for (int b = 0; b < BINS; ++b) {
            cx[b] += __shfl_down(cx[b], off, 64);
            cy[b] += __shfl_down(cy[b], off, 64);
        }
    }
    __shared__ double2 wred[16][BINS];
    if (lane == 0) {
#pragma unroll
        for (int b = 0; b < BINS; ++b) wred[wid][b] = make_double2(cx[b], cy[b]);
    }
    __syncthreads();
    if (tid == 0) {
        int nz = 0;
        double acc = 0.0;
#pragma unroll
        for (int b = 0; b < BINS; ++b) {
            double c = 0.0, s = 0.0;
            for (int w = 0; w < 16; ++w) { c += wred[w][b].x; s += wred[w][b].y; }
            if (c > 0.0) { nz++; acc += s / c; }
        }
        out[0] = (float)((nz > 0) ? (acc / (double)nz) : 0.0);
    }
}

__global__ void ghmc_final_atomic(const double* __restrict__ ws, float* __restrict__ out) {
    if (threadIdx.x == 0) {
        int nz = 0;
        double acc = 0.0;
#pragma unroll
        for (int b = 0; b < BINS; ++b) {
            double c = ws[b];
            if (c > 0.0) { nz++; acc += ws[BINS + b] / c; }
        }
        out[0] = (float)((nz > 0) ? (acc / (double)nz) : 0.0);
    }
}

extern "C" void kernel_launch(void* const* d_in, const int* in_sizes, int n_in,
                              void* d_out, int out_size, void* d_ws, size_t ws_size,
                              hipStream_t stream) {
    const float* pred = (const float*)d_in[0];   // [N,2] float32
    const int* target = (const int*)d_in[1];     // [N] int32 (harness lowers int64)
    const int nRows = in_sizes[1];
    const int nQuads = nRows / 4;
    float* out = (float*)d_out;

    const size_t need = (size_t)GRID * BINS * sizeof(float2);  // 160 KiB
    if (ws_size >= need) {
        float2* partials = (float2*)d_ws;
        ghmc_main<0><<<GRID, BLOCK, 0, stream>>>(
            (const float4*)pred, (const int4*)target, partials, nullptr, nQuads, nRows);
        ghmc_final_grid<<<1, 1024, 0, stream>>>(partials, out, GRID);
    } else {
        double* wsd = (double*)d_ws;
        ghmc_init<<<1, 64, 0, stream>>>(wsd);
        ghmc_main<1><<<GRID, BLOCK, 0, stream>>>(
            (const float4*)pred, (const int4*)target, nullptr, wsd, nQuads, nRows);
        ghmc_final_atomic<<<1, 64, 0, stream>>>(wsd, out);
    }
}